// Round 9
// baseline (124.206 us; speedup 1.0000x reference)
//
#include <hip/hip_runtime.h>
#include <hip/hip_bf16.h>

#define B_ 8
#define S_ 2048
#define D_ 1024
#define H_ 64

typedef __attribute__((ext_vector_type(8))) short bf16x8;
typedef __attribute__((ext_vector_type(4))) float f32x4;
typedef __attribute__((ext_vector_type(4))) unsigned short u16x4;
typedef unsigned short u16;
typedef unsigned int u32;

// fold 1/sqrt(64) and log2(e) into Q so softmax can use exp2
#define QSCALE 0.18033688011112042f

static __device__ __forceinline__ u16 f2bf(float f) {
  union { float f; unsigned u; } v; v.f = f;
  unsigned r = v.u + 0x7FFFu + ((v.u >> 16) & 1u);
  return (u16)(r >> 16);
}

// Build Wt [192][1024] bf16: rows 0..63 = Wq cols, 64..127 = Wk, 128..191 = Wv.
__global__ __launch_bounds__(256) void wprep_kernel(const float* __restrict__ Wk,
                                                    const float* __restrict__ Wq,
                                                    const float* __restrict__ Wv,
                                                    u16* __restrict__ Wt) {
  const int c = blockIdx.x;  // 0..191
  const float* W = (c < 64) ? Wq : ((c < 128) ? Wk : Wv);
  const int cc = c & 63;
  for (int d = threadIdx.x; d < D_; d += blockDim.x)
    Wt[c * D_ + d] = f2bf(W[d * H_ + cc]);
}

// QKV v7: one block computes ALL 192 cols -> x read exactly once from HBM.
// Block = 512 threads = 8 waves = 4 col-groups (48 cols) x 2 K-slices (512 k).
// W: 48 bf16x8 (192 VGPR) per wave, hoisted once. x: 16-row chunks (64 KB)
// double-buffered in LDS via global_load_lds with involutive source swizzle.
// Grid = 256 blocks x 4 grid-strided chunks; 1 block/CU.
__global__ __launch_bounds__(512, 2) void qkv_kernel(const float* __restrict__ x,
                                                     const u16* __restrict__ Wt,
                                                     u16* __restrict__ Qb,
                                                     u16* __restrict__ Kb,
                                                     u16* __restrict__ Vt) {
  __shared__ float xbuf[2][16384];   // 128 KB
  __shared__ float red[4][64][12];   // 12.25 KB

  const int tid = threadIdx.x;
  const int w = tid >> 6;
  const int lane = tid & 63;
  const int r = lane & 15;
  const int g = lane >> 4;
  const int cg = w & 3;    // col-group: cols 48*cg .. +47
  const int ks = w >> 2;   // k-slice: k in [ks*512, ks*512+512)
  const int rswz = (r & 7) << 4;

  // ---- W fragments, loaded ONCE, register-resident (48 x bf16x8) ----
  const u16* wbase = Wt + (size_t)(cg * 48 + r) * D_ + ks * 512 + g * 8;
  bf16x8 wf[3][16];
#pragma unroll
  for (int nf = 0; nf < 3; ++nf)
#pragma unroll
    for (int s = 0; s < 16; ++s)
      wf[nf][s] = *(const bf16x8*)(wbase + (size_t)nf * 16 * D_ + s * 32);

  // Stage one 16-row chunk (64 KB contiguous) with source pre-swizzle
  // L -> L ^ ((row&7)<<4) so swizzled ds_reads see linear data.
#define STAGE(chunk, buf)                                                     \
  {                                                                           \
    const char* gbase = (const char*)x + (size_t)(chunk) * 65536;             \
    _Pragma("unroll") for (int j = 0; j < 8; ++j) {                           \
      const int L = j * 8192 + tid * 16;                                      \
      const int Ls = L ^ (((L >> 12) & 7) << 4);                              \
      __builtin_amdgcn_global_load_lds(                                       \
          (const __attribute__((address_space(1))) u32*)(gbase + Ls),         \
          (__attribute__((address_space(3))) u32*)((char*)&xbuf[buf][0] + L), \
          16, 0, 0);                                                          \
    }                                                                         \
  }

  STAGE(blockIdx.x, 0);
  int cur = 0;

  for (int i = 0; i < 4; ++i) {
    const long row0 = ((long)blockIdx.x + (long)i * 256) * 16;
    __syncthreads();  // xbuf[cur] ready
    if (i < 3) STAGE(blockIdx.x + (i + 1) * 256, cur ^ 1);

    const char* xb = (const char*)&xbuf[cur][0];
    f32x4 a0 = (f32x4){0.f, 0.f, 0.f, 0.f};
    f32x4 a1 = a0, a2 = a0;
#pragma unroll
    for (int s = 0; s < 16; ++s) {
      const int alin = r * 4096 + (ks * 512 + s * 32 + g * 8) * 4;
      const float4 lo = *(const float4*)(xb + (alin ^ rswz));
      const float4 hi = *(const float4*)(xb + ((alin + 16) ^ rswz));
      bf16x8 a;
      a[0] = (short)f2bf(lo.x); a[1] = (short)f2bf(lo.y);
      a[2] = (short)f2bf(lo.z); a[3] = (short)f2bf(lo.w);
      a[4] = (short)f2bf(hi.x); a[5] = (short)f2bf(hi.y);
      a[6] = (short)f2bf(hi.z); a[7] = (short)f2bf(hi.w);
      a0 = __builtin_amdgcn_mfma_f32_16x16x32_bf16(a, wf[0][s], a0, 0, 0, 0);
      a1 = __builtin_amdgcn_mfma_f32_16x16x32_bf16(a, wf[1][s], a1, 0, 0, 0);
      a2 = __builtin_amdgcn_mfma_f32_16x16x32_bf16(a, wf[2][s], a2, 0, 0, 0);
    }

    // ---- reduce over the 2 k-slices ----
    if (ks == 1) {
      float* dst = &red[cg][lane][0];
      *(f32x4*)&dst[0] = a0; *(f32x4*)&dst[4] = a1; *(f32x4*)&dst[8] = a2;
    }
    __syncthreads();
    if (ks == 0) {
      const float* src = &red[cg][lane][0];
      a0 += *(const f32x4*)&src[0];
      a1 += *(const f32x4*)&src[4];
      a2 += *(const f32x4*)&src[8];

      const int bb = (int)(row0 >> 11);
      const int srow = (int)(row0 & 2047);
      f32x4 sv[3] = {a0, a1, a2};
#pragma unroll
      for (int nf = 0; nf < 3; ++nf) {
        const int col = cg * 48 + nf * 16 + r;  // frag wholly in Q, K, or V
        if (col < 64) {
#pragma unroll
          for (int ii = 0; ii < 4; ++ii)
            Qb[(row0 + 4 * g + ii) * H_ + col] = f2bf(sv[nf][ii] * QSCALE);
        } else if (col < 128) {
#pragma unroll
          for (int ii = 0; ii < 4; ++ii)
            Kb[(row0 + 4 * g + ii) * H_ + (col - 64)] = f2bf(sv[nf][ii]);
        } else {
          u16x4 vp;
#pragma unroll
          for (int ii = 0; ii < 4; ++ii) vp[ii] = f2bf(sv[nf][ii]);
          *(u16x4*)(Vt + ((size_t)(bb * H_ + (col - 128))) * S_ + srow + 4 * g) = vp;
        }
      }
    }
    cur ^= 1;
  }
#undef STAGE
}

// MFMA causal flash attention: attn3 core (operand order, 16-lane-shuffle
// softmax, LDS P path) with 4-way kv-split partition.
// Block = 4 waves = one 16-row q-tile x 4 kv-quarters; grid = 8 x 128 = 1024.
__global__ __launch_bounds__(256, 4) void attn5_kernel(const u16* __restrict__ Qb,
                                                       const u16* __restrict__ Kb,
                                                       const u16* __restrict__ Vt,
                                                       float* __restrict__ out) {
  __shared__ u16 plds[4][16 * 72];
  __shared__ float plo[4][16][68];
  __shared__ float pml[4][2][16];

  const int b = blockIdx.x >> 7;
  const int qt = blockIdx.x & 127;
  const int w = threadIdx.x >> 6;
  const int lane = threadIdx.x & 63;
  const int r = lane & 15;
  const int g = lane >> 4;
  const int q0 = qt << 4;
  const int T = (qt >> 2) + 1;          // # of 64-wide kv tiles
  const int start = (w * T) >> 2;
  const int end = ((w + 1) * T) >> 2;

  // Q A-fragments (hoisted)
  const u16* Qp = Qb + ((long)(b * S_ + q0 + r)) * H_ + 8 * g;
  const bf16x8 aq0 = *(const bf16x8*)Qp;
  const bf16x8 aq1 = *(const bf16x8*)(Qp + 32);

  const u16* Kbase = Kb + (long)b * S_ * H_ + (long)r * H_ + 8 * g;
  const u16* Vbase = Vt + (long)b * H_ * S_ + (long)r * S_ + 8 * g;

  f32x4 o[4];
#pragma unroll
  for (int nf = 0; nf < 4; ++nf) o[nf] = (f32x4){0.f, 0.f, 0.f, 0.f};
  float mrow[4] = {-INFINITY, -INFINITY, -INFINITY, -INFINITY};
  float lrow[4] = {0.f, 0.f, 0.f, 0.f};

  u16* pw = plds[w];

  bf16x8 kc[8];
  if (start < end) {
    const int k0 = start << 6;
#pragma unroll
    for (int nf = 0; nf < 4; ++nf) {
      const u16* Kp = Kbase + (long)(k0 + nf * 16) * H_;
      kc[2 * nf] = *(const bf16x8*)(Kp);
      kc[2 * nf + 1] = *(const bf16x8*)(Kp + 32);
    }
  }

  for (int kt = start; kt < end; ++kt) {
    const int k0 = kt << 6;

    // ---- QK^T ----
    f32x4 sf[4];
#pragma unroll
    for (int nf = 0; nf < 4; ++nf) {
      f32x4 t = (f32x4){0.f, 0.f, 0.f, 0.f};
      t = __builtin_amdgcn_mfma_f32_16x16x32_bf16(aq0, kc[2 * nf], t, 0, 0, 0);
      t = __builtin_amdgcn_mfma_f32_16x16x32_bf16(aq1, kc[2 * nf + 1], t, 0, 0, 0);
      sf[nf] = t;
    }

    // ---- early V loads (fly under softmax) ----
    bf16x8 vv[8];
#pragma unroll
    for (int nf = 0; nf < 4; ++nf) {
      const u16* Vp = Vbase + (long)(nf * 16) * S_ + k0;
      vv[2 * nf] = *(const bf16x8*)(Vp);
      vv[2 * nf + 1] = *(const bf16x8*)(Vp + 32);
    }
    // ---- prefetch next K tile ----
    if (kt + 1 < end) {
      const int kn = (kt + 1) << 6;
#pragma unroll
      for (int nf = 0; nf < 4; ++nf) {
        const u16* Kp = Kbase + (long)(kn + nf * 16) * H_;
        kc[2 * nf] = *(const bf16x8*)(Kp);
        kc[2 * nf + 1] = *(const bf16x8*)(Kp + 32);
      }
    }

    if (kt == T - 1) {  // diagonal tile: causal mask
#pragma unroll
      for (int nf = 0; nf < 4; ++nf)
#pragma unroll
        for (int i = 0; i < 4; ++i) {
          const int k = k0 + nf * 16 + r;
          const int q = q0 + 4 * g + i;
          if (k > q) sf[nf][i] = -INFINITY;
        }
    }

    // ---- online softmax (rows in 16-lane groups) ----
    float fm[4];
#pragma unroll
    for (int i = 0; i < 4; ++i)
      fm[i] = fmaxf(fmaxf(sf[0][i], sf[1][i]), fmaxf(sf[2][i], sf[3][i]));
#pragma unroll
    for (int off = 8; off >= 1; off >>= 1)
#pragma unroll
      for (int i = 0; i < 4; ++i)
        fm[i] = fmaxf(fm[i], __shfl_xor(fm[i], off));

    float sc[4];
#pragma unroll
    for (int i = 0; i < 4; ++i) {
      const float mn = fmaxf(mrow[i], fm[i]);
      sc[i] = exp2f(mrow[i] - mn);
      mrow[i] = mn;
    }

    float ps[4] = {0.f, 0.f, 0.f, 0.f};
#pragma unroll
    for (int nf = 0; nf < 4; ++nf)
#pragma unroll
      for (int i = 0; i < 4; ++i) {
        const float p = exp2f(sf[nf][i] - mrow[i]);
        sf[nf][i] = p;
        ps[i] += p;
      }
#pragma unroll
    for (int off = 8; off >= 1; off >>= 1)
#pragma unroll
      for (int i = 0; i < 4; ++i)
        ps[i] += __shfl_xor(ps[i], off);

#pragma unroll
    for (int i = 0; i < 4; ++i) lrow[i] = lrow[i] * sc[i] + ps[i];
#pragma unroll
    for (int nf = 0; nf < 4; ++nf)
#pragma unroll
      for (int i = 0; i < 4; ++i) o[nf][i] *= sc[i];

    // ---- P -> LDS (bf16), re-fragment as PV A-operand ----
#pragma unroll
    for (int nf = 0; nf < 4; ++nf)
#pragma unroll
      for (int i = 0; i < 4; ++i)
        pw[(4 * g + i) * 72 + nf * 16 + r] = f2bf(sf[nf][i]);

    const bf16x8 pa0 = *(const bf16x8*)(pw + r * 72 + 8 * g);
    const bf16x8 pa1 = *(const bf16x8*)(pw + r * 72 + 32 + 8 * g);

    // ---- PV ----
#pragma unroll
    for (int nf = 0; nf < 4; ++nf) {
      o[nf] = __builtin_amdgcn_mfma_f32_16x16x32_bf16(pa0, vv[2 * nf], o[nf], 0, 0, 0);
      o[nf] = __builtin_amdgcn_mfma_f32_16x16x32_bf16(pa1, vv[2 * nf + 1], o[nf], 0, 0, 0);
    }
  }

  // ---- write partials to LDS ----
#pragma unroll
  for (int nf = 0; nf < 4; ++nf)
#pragma unroll
    for (int i = 0; i < 4; ++i)
      plo[w][4 * g + i][nf * 16 + r] = o[nf][i];
  if (r == 0) {
#pragma unroll
    for (int i = 0; i < 4; ++i) {
      pml[w][0][4 * g + i] = mrow[i];
      pml[w][1][4 * g + i] = lrow[i];
    }
  }
  __syncthreads();

  // ---- 4-way merge; thread -> (row, 4 cols) ----
  const int row = (w << 2) + g;
  const int c0 = r << 2;
  const float m0 = pml[0][0][row], m1 = pml[1][0][row];
  const float m2 = pml[2][0][row], m3 = pml[3][0][row];
  const float M = fmaxf(fmaxf(m0, m1), fmaxf(m2, m3));
  const float e0 = exp2f(m0 - M), e1 = exp2f(m1 - M);
  const float e2 = exp2f(m2 - M), e3 = exp2f(m3 - M);
  const float L = pml[0][1][row] * e0 + pml[1][1][row] * e1 +
                  pml[2][1][row] * e2 + pml[3][1][row] * e3;
  const float inv = 1.f / L;
  f32x4 os;
#pragma unroll
  for (int c = 0; c < 4; ++c)
    os[c] = (plo[0][row][c0 + c] * e0 + plo[1][row][c0 + c] * e1 +
             plo[2][row][c0 + c] * e2 + plo[3][row][c0 + c] * e3) * inv;
  *(f32x4*)(out + ((long)(b * S_ + q0 + row)) * H_ + c0) = os;
}

extern "C" void kernel_launch(void* const* d_in, const int* in_sizes, int n_in,
                              void* d_out, int out_size, void* d_ws, size_t ws_size,
                              hipStream_t stream) {
  const float* x  = (const float*)d_in[0];
  const float* Wk = (const float*)d_in[1];
  const float* Wq = (const float*)d_in[2];
  const float* Wv = (const float*)d_in[3];
  float* out = (float*)d_out;

  u16* Qb = (u16*)d_ws;                                   // 2 MiB
  u16* Kb = Qb + (long)B_ * S_ * H_;                      // 2 MiB
  u16* Vt = Kb + (long)B_ * S_ * H_;                      // 2 MiB
  u16* Wt = Vt + (long)B_ * S_ * H_;                      // 384 KiB

  wprep_kernel<<<192, 256, 0, stream>>>(Wk, Wq, Wv, Wt);
  qkv_kernel<<<256, 512, 0, stream>>>(x, Wt, Qb, Kb, Vt);
  attn5_kernel<<<B_ * 128, 256, 0, stream>>>(Qb, Kb, Vt, out);
}

// Round 10
// 80.669 us; speedup vs baseline: 1.5397x; 1.5397x over previous
//
#include <hip/hip_runtime.h>
#include <hip/hip_bf16.h>

#define B_ 8
#define S_ 2048
#define D_ 1024
#define H_ 64

typedef __attribute__((ext_vector_type(8))) short bf16x8;
typedef __attribute__((ext_vector_type(4))) float f32x4;
typedef __attribute__((ext_vector_type(4))) unsigned short u16x4;
typedef unsigned short u16;
typedef unsigned int u32;

// fold 1/sqrt(64) and log2(e) into Q so softmax can use exp2
#define QSCALE 0.18033688011112042f

static __device__ __forceinline__ u16 f2bf(float f) {
  union { float f; unsigned u; } v; v.f = f;
  unsigned r = v.u + 0x7FFFu + ((v.u >> 16) & 1u);
  return (u16)(r >> 16);
}

// Build Wt [192][1024] bf16: rows 0..63 = Wq cols, 64..127 = Wk, 128..191 = Wv.
__global__ __launch_bounds__(256) void wprep_kernel(const float* __restrict__ Wk,
                                                    const float* __restrict__ Wq,
                                                    const float* __restrict__ Wv,
                                                    u16* __restrict__ Wt) {
  const int c = blockIdx.x;  // 0..191
  const float* W = (c < 64) ? Wq : ((c < 128) ? Wk : Wv);
  const int cc = c & 63;
  for (int d = threadIdx.x; d < D_; d += blockDim.x)
    Wt[c * D_ + d] = f2bf(W[d * H_ + cc]);
}

// QKV v10: fully LDS-DMA-staged pipeline — NO VMEM in the compute phase.
// Block = 256 threads = 4 waves = 2 row-groups (16 rows) x 2 col-halves (96).
// Per chunk (BK=64): barrier (stage kc done) -> issue stage kc+1 (x + W via
// global_load_lds, XOR-swizzled source) -> compute purely from LDS.
// No K-split, no reduce, one barrier per chunk. Grid = 512 blocks (32 rows).
__global__ __launch_bounds__(256) void qkv_kernel(const float* __restrict__ x,
                                                  const u16* __restrict__ Wt,
                                                  u16* __restrict__ Qb,
                                                  u16* __restrict__ Kb,
                                                  u16* __restrict__ Vt) {
  __shared__ char sh[65536];  // xs: 2 x [32][64] f32 (16 KB); ws: 2 x [192][64] bf16 (48 KB)
  char* const xsb = sh;
  char* const wsb = sh + 16384;

  const int tid = threadIdx.x;
  const int w = tid >> 6;
  const int lane = tid & 63;
  const int r = lane & 15;
  const int g = lane >> 4;
  const int rg = w >> 1;   // row-group 0/1
  const int ch = w & 1;    // col-half 0/1

  const long row0 = (long)blockIdx.x * 32;

  // x tile [32 rows][64 k] fp32, row stride 256 B; swizzle bits 4-6 by row&7.
#define STAGE_X(kc, buf)                                                       \
  {                                                                            \
    const char* gb = (const char*)x + (size_t)row0 * 4096 + (size_t)(kc) * 256;\
    _Pragma("unroll") for (int j = 0; j < 2; ++j) {                            \
      const int L = j * 4096 + tid * 16;                                       \
      const int row = L >> 8;                                                  \
      const int sw = (L & 255) ^ ((row & 7) << 4);                             \
      __builtin_amdgcn_global_load_lds(                                        \
          (const __attribute__((address_space(1))) u32*)(gb + (size_t)row * 4096 + sw), \
          (__attribute__((address_space(3))) u32*)(xsb + (buf) * 8192 + L),    \
          16, 0, 0);                                                           \
    }                                                                          \
  }

  // W tile [192 cols][64 k] bf16, col stride 128 B; swizzle bits 4-6 by col&7.
#define STAGE_W(kc, buf)                                                       \
  {                                                                            \
    const char* gb = (const char*)Wt + (size_t)(kc) * 128;                     \
    _Pragma("unroll") for (int j = 0; j < 6; ++j) {                            \
      const int L = j * 4096 + tid * 16;                                       \
      const int col = L >> 7;                                                  \
      const int sw = (L & 127) ^ ((col & 7) << 4);                             \
      __builtin_amdgcn_global_load_lds(                                        \
          (const __attribute__((address_space(1))) u32*)(gb + (size_t)col * 2048 + sw), \
          (__attribute__((address_space(3))) u32*)(wsb + (buf) * 24576 + L),   \
          16, 0, 0);                                                           \
    }                                                                          \
  }

  f32x4 acc[6];
#pragma unroll
  for (int nf = 0; nf < 6; ++nf) acc[nf] = (f32x4){0.f, 0.f, 0.f, 0.f};

  STAGE_X(0, 0);
  STAGE_W(0, 0);
  int cur = 0;

  const int rr = rg * 16 + r;
  const int xswz = (rr & 7) << 4;

  for (int kc = 0; kc < 16; ++kc) {
    __syncthreads();  // stage(kc) complete (vmcnt drained here, by design)
    if (kc < 15) {
      STAGE_X(kc + 1, cur ^ 1);
      STAGE_W(kc + 1, cur ^ 1);
    }
    __builtin_amdgcn_sched_barrier(0);  // keep stage issue above compute

    const char* xb = xsb + cur * 8192;
    const char* wb = wsb + cur * 24576;
#pragma unroll
    for (int ks = 0; ks < 2; ++ks) {
      const int cb = ks * 128 + g * 32;
      const float4 lo = *(const float4*)(xb + rr * 256 + (cb ^ xswz));
      const float4 hi = *(const float4*)(xb + rr * 256 + ((cb + 16) ^ xswz));
      bf16x8 a;
      a[0] = (short)f2bf(lo.x); a[1] = (short)f2bf(lo.y);
      a[2] = (short)f2bf(lo.z); a[3] = (short)f2bf(lo.w);
      a[4] = (short)f2bf(hi.x); a[5] = (short)f2bf(hi.y);
      a[6] = (short)f2bf(hi.z); a[7] = (short)f2bf(hi.w);
#pragma unroll
      for (int nf = 0; nf < 6; ++nf) {
        const int col = ch * 96 + nf * 16 + r;
        const int wcb = (ks * 64 + g * 16) ^ ((col & 7) << 4);
        const bf16x8 b = *(const bf16x8*)(wb + col * 128 + wcb);
        acc[nf] = __builtin_amdgcn_mfma_f32_16x16x32_bf16(a, b, acc[nf], 0, 0, 0);
      }
    }
    cur ^= 1;
  }
#undef STAGE_W
#undef STAGE_X

  // ---- epilogue: each wave owns rows rg*16.., cols ch*96..+95 exclusively ----
  const int bb = (int)(row0 >> 11);
  const int srow = (int)(row0 & 2047) + rg * 16;
#pragma unroll
  for (int nf = 0; nf < 6; ++nf) {
    const int col = ch * 96 + nf * 16 + r;  // frag wholly in Q, K, or V
    if (col < 64) {
#pragma unroll
      for (int ii = 0; ii < 4; ++ii)
        Qb[(row0 + rg * 16 + 4 * g + ii) * H_ + col] = f2bf(acc[nf][ii] * QSCALE);
    } else if (col < 128) {
#pragma unroll
      for (int ii = 0; ii < 4; ++ii)
        Kb[(row0 + rg * 16 + 4 * g + ii) * H_ + (col - 64)] = f2bf(acc[nf][ii]);
    } else {
      u16x4 vp;
#pragma unroll
      for (int ii = 0; ii < 4; ++ii) vp[ii] = f2bf(acc[nf][ii]);
      *(u16x4*)(Vt + ((size_t)(bb * H_ + (col - 128))) * S_ + srow + 4 * g) = vp;
    }
  }
}

// MFMA causal flash attention: attn3 core with 4-way kv-split partition.
// Block = 4 waves = one 16-row q-tile x 4 kv-quarters; grid = 8 x 128 = 1024.
// (256,2): cap 256 — room for VGPR + AGPR (unified file; (256,4)'s cap 128
// forced serial K/V reloads in round 9).
__global__ __launch_bounds__(256, 2) void attn5_kernel(const u16* __restrict__ Qb,
                                                       const u16* __restrict__ Kb,
                                                       const u16* __restrict__ Vt,
                                                       float* __restrict__ out) {
  __shared__ u16 plds[4][16 * 72];
  __shared__ float plo[4][16][68];
  __shared__ float pml[4][2][16];

  const int b = blockIdx.x >> 7;
  const int qt = blockIdx.x & 127;
  const int w = threadIdx.x >> 6;
  const int lane = threadIdx.x & 63;
  const int r = lane & 15;
  const int g = lane >> 4;
  const int q0 = qt << 4;
  const int T = (qt >> 2) + 1;          // # of 64-wide kv tiles
  const int start = (w * T) >> 2;
  const int end = ((w + 1) * T) >> 2;

  // Q A-fragments (hoisted)
  const u16* Qp = Qb + ((long)(b * S_ + q0 + r)) * H_ + 8 * g;
  const bf16x8 aq0 = *(const bf16x8*)Qp;
  const bf16x8 aq1 = *(const bf16x8*)(Qp + 32);

  const u16* Kbase = Kb + (long)b * S_ * H_ + (long)r * H_ + 8 * g;
  const u16* Vbase = Vt + (long)b * H_ * S_ + (long)r * S_ + 8 * g;

  f32x4 o[4];
#pragma unroll
  for (int nf = 0; nf < 4; ++nf) o[nf] = (f32x4){0.f, 0.f, 0.f, 0.f};
  float mrow[4] = {-INFINITY, -INFINITY, -INFINITY, -INFINITY};
  float lrow[4] = {0.f, 0.f, 0.f, 0.f};

  u16* pw = plds[w];

  bf16x8 kc[8];
  if (start < end) {
    const int k0 = start << 6;
#pragma unroll
    for (int nf = 0; nf < 4; ++nf) {
      const u16* Kp = Kbase + (long)(k0 + nf * 16) * H_;
      kc[2 * nf] = *(const bf16x8*)(Kp);
      kc[2 * nf + 1] = *(const bf16x8*)(Kp + 32);
    }
  }

  for (int kt = start; kt < end; ++kt) {
    const int k0 = kt << 6;

    // ---- QK^T ----
    f32x4 sf[4];
#pragma unroll
    for (int nf = 0; nf < 4; ++nf) {
      f32x4 t = (f32x4){0.f, 0.f, 0.f, 0.f};
      t = __builtin_amdgcn_mfma_f32_16x16x32_bf16(aq0, kc[2 * nf], t, 0, 0, 0);
      t = __builtin_amdgcn_mfma_f32_16x16x32_bf16(aq1, kc[2 * nf + 1], t, 0, 0, 0);
      sf[nf] = t;
    }

    // ---- early V loads (fly under softmax) ----
    bf16x8 vv[8];
#pragma unroll
    for (int nf = 0; nf < 4; ++nf) {
      const u16* Vp = Vbase + (long)(nf * 16) * S_ + k0;
      vv[2 * nf] = *(const bf16x8*)(Vp);
      vv[2 * nf + 1] = *(const bf16x8*)(Vp + 32);
    }
    // ---- prefetch next K tile ----
    if (kt + 1 < end) {
      const int kn = (kt + 1) << 6;
#pragma unroll
      for (int nf = 0; nf < 4; ++nf) {
        const u16* Kp = Kbase + (long)(kn + nf * 16) * H_;
        kc[2 * nf] = *(const bf16x8*)(Kp);
        kc[2 * nf + 1] = *(const bf16x8*)(Kp + 32);
      }
    }

    if (kt == T - 1) {  // diagonal tile: causal mask
#pragma unroll
      for (int nf = 0; nf < 4; ++nf)
#pragma unroll
        for (int i = 0; i < 4; ++i) {
          const int k = k0 + nf * 16 + r;
          const int q = q0 + 4 * g + i;
          if (k > q) sf[nf][i] = -INFINITY;
        }
    }

    // ---- online softmax (rows in 16-lane groups) ----
    float fm[4];
#pragma unroll
    for (int i = 0; i < 4; ++i)
      fm[i] = fmaxf(fmaxf(sf[0][i], sf[1][i]), fmaxf(sf[2][i], sf[3][i]));
#pragma unroll
    for (int off = 8; off >= 1; off >>= 1)
#pragma unroll
      for (int i = 0; i < 4; ++i)
        fm[i] = fmaxf(fm[i], __shfl_xor(fm[i], off));

    float sc[4];
#pragma unroll
    for (int i = 0; i < 4; ++i) {
      const float mn = fmaxf(mrow[i], fm[i]);
      sc[i] = exp2f(mrow[i] - mn);
      mrow[i] = mn;
    }

    float ps[4] = {0.f, 0.f, 0.f, 0.f};
#pragma unroll
    for (int nf = 0; nf < 4; ++nf)
#pragma unroll
      for (int i = 0; i < 4; ++i) {
        const float p = exp2f(sf[nf][i] - mrow[i]);
        sf[nf][i] = p;
        ps[i] += p;
      }
#pragma unroll
    for (int off = 8; off >= 1; off >>= 1)
#pragma unroll
      for (int i = 0; i < 4; ++i)
        ps[i] += __shfl_xor(ps[i], off);

#pragma unroll
    for (int i = 0; i < 4; ++i) lrow[i] = lrow[i] * sc[i] + ps[i];
#pragma unroll
    for (int nf = 0; nf < 4; ++nf)
#pragma unroll
      for (int i = 0; i < 4; ++i) o[nf][i] *= sc[i];

    // ---- P -> LDS (bf16), re-fragment as PV A-operand ----
#pragma unroll
    for (int nf = 0; nf < 4; ++nf)
#pragma unroll
      for (int i = 0; i < 4; ++i)
        pw[(4 * g + i) * 72 + nf * 16 + r] = f2bf(sf[nf][i]);

    const bf16x8 pa0 = *(const bf16x8*)(pw + r * 72 + 8 * g);
    const bf16x8 pa1 = *(const bf16x8*)(pw + r * 72 + 32 + 8 * g);

    // ---- PV ----
#pragma unroll
    for (int nf = 0; nf < 4; ++nf) {
      o[nf] = __builtin_amdgcn_mfma_f32_16x16x32_bf16(pa0, vv[2 * nf], o[nf], 0, 0, 0);
      o[nf] = __builtin_amdgcn_mfma_f32_16x16x32_bf16(pa1, vv[2 * nf + 1], o[nf], 0, 0, 0);
    }
  }

  // ---- write partials to LDS ----
#pragma unroll
  for (int nf = 0; nf < 4; ++nf)
#pragma unroll
    for (int i = 0; i < 4; ++i)
      plo[w][4 * g + i][nf * 16 + r] = o[nf][i];
  if (r == 0) {
#pragma unroll
    for (int i = 0; i < 4; ++i) {
      pml[w][0][4 * g + i] = mrow[i];
      pml[w][1][4 * g + i] = lrow[i];
    }
  }
  __syncthreads();

  // ---- 4-way merge; thread -> (row, 4 cols) ----
  const int row = (w << 2) + g;
  const int c0 = r << 2;
  const float m0 = pml[0][0][row], m1 = pml[1][0][row];
  const float m2 = pml[2][0][row], m3 = pml[3][0][row];
  const float M = fmaxf(fmaxf(m0, m1), fmaxf(m2, m3));
  const float e0 = exp2f(m0 - M), e1 = exp2f(m1 - M);
  const float e2 = exp2f(m2 - M), e3 = exp2f(m3 - M);
  const float L = pml[0][1][row] * e0 + pml[1][1][row] * e1 +
                  pml[2][1][row] * e2 + pml[3][1][row] * e3;
  const float inv = 1.f / L;
  f32x4 os;
#pragma unroll
  for (int c = 0; c < 4; ++c)
    os[c] = (plo[0][row][c0 + c] * e0 + plo[1][row][c0 + c] * e1 +
             plo[2][row][c0 + c] * e2 + plo[3][row][c0 + c] * e3) * inv;
  *(f32x4*)(out + ((long)(b * S_ + q0 + row)) * H_ + c0) = os;
}

extern "C" void kernel_launch(void* const* d_in, const int* in_sizes, int n_in,
                              void* d_out, int out_size, void* d_ws, size_t ws_size,
                              hipStream_t stream) {
  const float* x  = (const float*)d_in[0];
  const float* Wk = (const float*)d_in[1];
  const float* Wq = (const float*)d_in[2];
  const float* Wv = (const float*)d_in[3];
  float* out = (float*)d_out;

  u16* Qb = (u16*)d_ws;                                   // 2 MiB
  u16* Kb = Qb + (long)B_ * S_ * H_;                      // 2 MiB
  u16* Vt = Kb + (long)B_ * S_ * H_;                      // 2 MiB
  u16* Wt = Vt + (long)B_ * S_ * H_;                      // 384 KiB

  wprep_kernel<<<192, 256, 0, stream>>>(Wk, Wq, Wv, Wt);
  qkv_kernel<<<512, 256, 0, stream>>>(x, Wt, Qb, Kb, Vt);
  attn5_kernel<<<B_ * 128, 256, 0, stream>>>(Qb, Kb, Vt, out);
}